// Round 1
// baseline (1752.514 us; speedup 1.0000x reference)
//
#include <hip/hip_runtime.h>
#include <math.h>

#define NN 50000      // nodes
#define NE 800000     // edges
#define NP 200000     // link pairs
#define NF 128        // feature dim
#define NEDGE_TOT (NE + NN)   // edges + self loops

// ---------------------------------------------------------------------------
// CSR build kernels
// ---------------------------------------------------------------------------

__global__ __launch_bounds__(256) void init_cnt_k(int* __restrict__ cnt) {
    int i = blockIdx.x * 256 + threadIdx.x;
    if (i < NN) cnt[i] = 1;  // self-loop contributes 1 to every node's in-degree
}

__global__ __launch_bounds__(256) void count_k(const int* __restrict__ ei,
                                               int* __restrict__ cnt) {
    int e = blockIdx.x * 256 + threadIdx.x;
    if (e < NE) atomicAdd(&cnt[ei[NE + e]], 1);  // dst row of edge_index
}

__global__ __launch_bounds__(256) void dinv_k(const int* __restrict__ cnt,
                                              float* __restrict__ dinv) {
    int i = blockIdx.x * 256 + threadIdx.x;
    if (i < NN) dinv[i] = rsqrtf((float)cnt[i]);  // deg >= 1 always
}

// single-block exclusive scan of cnt[NN] -> row_ptr[NN+1], wptr[NN]
__global__ __launch_bounds__(256) void scan_k(const int* __restrict__ cnt,
                                              int* __restrict__ row_ptr,
                                              int* __restrict__ wptr) {
    __shared__ int part[256];
    const int CH = (NN + 255) / 256;  // 196
    int t = threadIdx.x;
    int base = t * CH;
    int s = 0;
    for (int i = 0; i < CH; ++i) {
        int idx = base + i;
        if (idx < NN) s += cnt[idx];
    }
    part[t] = s;
    __syncthreads();
    for (int off = 1; off < 256; off <<= 1) {
        int add = (t >= off) ? part[t - off] : 0;
        __syncthreads();
        part[t] += add;
        __syncthreads();
    }
    int pre = (t == 0) ? 0 : part[t - 1];
    for (int i = 0; i < CH; ++i) {
        int idx = base + i;
        if (idx < NN) {
            row_ptr[idx] = pre;
            wptr[idx] = pre;
            pre += cnt[idx];
        }
    }
    if (t == 255) row_ptr[NN] = pre;  // == NEDGE_TOT
}

__global__ __launch_bounds__(256) void scatter_k(const int* __restrict__ ei,
                                                 const float* __restrict__ dinv,
                                                 int* __restrict__ wptr,
                                                 int* __restrict__ cols,
                                                 float* __restrict__ norms) {
    int e = blockIdx.x * 256 + threadIdx.x;
    if (e >= NEDGE_TOT) return;
    int s, d;
    if (e < NE) { s = ei[e]; d = ei[NE + e]; }
    else        { s = d = e - NE; }          // self-loops
    int pos = atomicAdd(&wptr[d], 1);
    cols[pos]  = s;
    norms[pos] = dinv[s] * dinv[d];
}

// ---------------------------------------------------------------------------
// Dense GEMM: Y[n,f] = sum_d X[n,d] * W[f,d] + bias[f]   (X:[nrows,128], W:[128,128])
// W staged transposed in LDS with XOR swizzle: sW[d*128 + (f ^ (d&31))]
//   - transpose-write phase: consecutive threads vary d, f fixed -> banks distinct
//   - compute-read phase: lanes vary f, d fixed -> 2-way (free)
// Each thread computes 2 rows x 1 feature; block handles 4 rows/iteration.
// ---------------------------------------------------------------------------
__global__ __launch_bounds__(256) void gemm128_k(const float* __restrict__ X,
                                                 const float* __restrict__ W,
                                                 const float* __restrict__ bias,
                                                 float* __restrict__ Y,
                                                 int nrows) {
    __shared__ float sW[128 * 128];  // 64 KiB
    for (int i = threadIdx.x; i < 128 * 128; i += 256) {
        int f = i >> 7, d = i & 127;
        sW[d * 128 + (f ^ (d & 31))] = W[i];
    }
    __syncthreads();
    int f = threadIdx.x & 127;
    int half = threadIdx.x >> 7;
    float bf = bias[f];
    for (int base = blockIdx.x * 4; base < nrows; base += gridDim.x * 4) {
        int r0 = base + half * 2;
        const float* xp0 = X + (size_t)r0 * NF;
        const float* xp1 = xp0 + NF;
        float acc0 = 0.f, acc1 = 0.f;
#pragma unroll
        for (int d = 0; d < 128; d += 4) {
            float4 xa = *(const float4*)(xp0 + d);
            float4 xb = *(const float4*)(xp1 + d);
            float w0 = sW[(d + 0) * 128 + (f ^ ((d + 0) & 31))];
            float w1 = sW[(d + 1) * 128 + (f ^ ((d + 1) & 31))];
            float w2 = sW[(d + 2) * 128 + (f ^ ((d + 2) & 31))];
            float w3 = sW[(d + 3) * 128 + (f ^ ((d + 3) & 31))];
            acc0 += w0 * xa.x + w1 * xa.y + w2 * xa.z + w3 * xa.w;
            acc1 += w0 * xb.x + w1 * xb.y + w2 * xb.z + w3 * xb.w;
        }
        Y[(size_t)r0 * NF + f] = acc0 + bf;
        Y[(size_t)(r0 + 1) * NF + f] = acc1 + bf;
    }
}

// ---------------------------------------------------------------------------
// APPNP step: out[v] = 0.9 * sum_{e in CSR row v} norm_e * h[col_e] + 0.1 * x0[v]
// One wave (64 lanes) per dst node; lane holds float2 (features 2*lane, 2*lane+1).
// Edge (col,norm) pairs loaded cooperatively, broadcast via __shfl; unroll x4.
// ---------------------------------------------------------------------------
__global__ __launch_bounds__(256) void appnp_step_k(const float* __restrict__ h,
                                                    const float* __restrict__ x0,
                                                    float* __restrict__ out,
                                                    const int* __restrict__ row_ptr,
                                                    const int* __restrict__ cols,
                                                    const float* __restrict__ norms,
                                                    int relu) {
    int gw = (blockIdx.x * 256 + threadIdx.x) >> 6;  // node id
    int lane = threadIdx.x & 63;
    if (gw >= NN) return;
    int beg = row_ptr[gw], end = row_ptr[gw + 1];
    float ax = 0.f, ay = 0.f;
    for (int e = beg; e < end; e += 64) {
        int m = end - e;
        if (m > 64) m = 64;
        int c = 0;
        float w = 0.f;
        if (lane < m) { c = cols[e + lane]; w = norms[e + lane]; }
        int j = 0;
        for (; j + 4 <= m; j += 4) {
            int c0 = __shfl(c, j, 64), c1 = __shfl(c, j + 1, 64);
            int c2 = __shfl(c, j + 2, 64), c3 = __shfl(c, j + 3, 64);
            float w0 = __shfl(w, j, 64), w1 = __shfl(w, j + 1, 64);
            float w2 = __shfl(w, j + 2, 64), w3 = __shfl(w, j + 3, 64);
            float2 h0 = *(const float2*)(h + (size_t)c0 * NF + lane * 2);
            float2 h1 = *(const float2*)(h + (size_t)c1 * NF + lane * 2);
            float2 h2 = *(const float2*)(h + (size_t)c2 * NF + lane * 2);
            float2 h3 = *(const float2*)(h + (size_t)c3 * NF + lane * 2);
            ax += w0 * h0.x + w1 * h1.x + w2 * h2.x + w3 * h3.x;
            ay += w0 * h0.y + w1 * h1.y + w2 * h2.y + w3 * h3.y;
        }
        for (; j < m; ++j) {
            int cc = __shfl(c, j, 64);
            float ww = __shfl(w, j, 64);
            float2 hv = *(const float2*)(h + (size_t)cc * NF + lane * 2);
            ax += ww * hv.x;
            ay += ww * hv.y;
        }
    }
    float2 xv = *(const float2*)(x0 + (size_t)gw * NF + lane * 2);
    float rx = 0.9f * ax + 0.1f * xv.x;
    float ry = 0.9f * ay + 0.1f * xv.y;
    if (relu) { rx = fmaxf(rx, 0.f); ry = fmaxf(ry, 0.f); }
    *(float2*)(out + (size_t)gw * NF + lane * 2) = make_float2(rx, ry);
}

// ---------------------------------------------------------------------------
// Pair head: one wave per pair.
// out[p] = log_softmax( [h[u], h[v]] @ W3.T + b3 )   (OUT = 2)
// ---------------------------------------------------------------------------
__global__ __launch_bounds__(256) void pair_k(const float* __restrict__ h,
                                              const int* __restrict__ index,
                                              const float* __restrict__ W3,
                                              const float* __restrict__ b3,
                                              float* __restrict__ outp) {
    int gw = (blockIdx.x * 256 + threadIdx.x) >> 6;  // pair id
    int lane = threadIdx.x & 63;
    if (gw >= NP) return;
    int u = index[gw * 2], v = index[gw * 2 + 1];
    const float* hu = h + (size_t)u * NF;
    const float* hv = h + (size_t)v * NF;
    float a0 = hu[lane], a1 = hu[lane + 64];
    float a2 = hv[lane], a3 = hv[lane + 64];
    float p0 = a0 * W3[lane] + a1 * W3[64 + lane] + a2 * W3[128 + lane] + a3 * W3[192 + lane];
    float p1 = a0 * W3[256 + lane] + a1 * W3[320 + lane] + a2 * W3[384 + lane] + a3 * W3[448 + lane];
#pragma unroll
    for (int off = 32; off > 0; off >>= 1) {
        p0 += __shfl_xor(p0, off, 64);
        p1 += __shfl_xor(p1, off, 64);
    }
    if (lane == 0) {
        float s0 = p0 + b3[0], s1 = p1 + b3[1];
        float m = fmaxf(s0, s1);
        float lse = m + logf(expf(s0 - m) + expf(s1 - m));
        *(float2*)(outp + (size_t)gw * 2) = make_float2(s0 - lse, s1 - lse);
    }
}

// ---------------------------------------------------------------------------
// Launch
// ---------------------------------------------------------------------------
extern "C" void kernel_launch(void* const* d_in, const int* in_sizes, int n_in,
                              void* d_out, int out_size, void* d_ws, size_t ws_size,
                              hipStream_t stream) {
    const float* x  = (const float*)d_in[0];
    const int* ei   = (const int*)d_in[1];
    const int* idx  = (const int*)d_in[2];
    const float* W1 = (const float*)d_in[3];
    const float* b1 = (const float*)d_in[4];
    const float* W2 = (const float*)d_in[5];
    const float* b2 = (const float*)d_in[6];
    const float* W3 = (const float*)d_in[7];
    const float* b3 = (const float*)d_in[8];
    float* out = (float*)d_out;

    char* ws = (char*)d_ws;
    size_t off = 0;
    auto alloc = [&](size_t bytes) -> void* {
        void* p = ws + off;
        off = (off + bytes + 255) & ~(size_t)255;
        return p;
    };
    int*   cnt     = (int*)  alloc(NN * sizeof(int));
    float* dinv    = (float*)alloc(NN * sizeof(float));
    int*   row_ptr = (int*)  alloc((NN + 1) * sizeof(int));
    int*   wptr    = (int*)  alloc(NN * sizeof(int));
    int*   cols    = (int*)  alloc(NEDGE_TOT * sizeof(int));
    float* norms   = (float*)alloc(NEDGE_TOT * sizeof(float));
    float* H0      = (float*)alloc((size_t)NN * NF * sizeof(float));
    float* HA      = (float*)alloc((size_t)NN * NF * sizeof(float));
    float* HB      = (float*)alloc((size_t)NN * NF * sizeof(float));

    const int gN   = (NN + 255) / 256;          // 196
    const int gE   = (NE + 255) / 256;          // 3125
    const int gET  = (NEDGE_TOT + 255) / 256;   // 3321
    const int gStep = (NN * 64 + 255) / 256;    // 12500 (wave per node)
    const int gPair = (NP * 64 + 255) / 256;    // 50000 (wave per pair)

    // ---- gcn_norm + CSR build ----
    init_cnt_k<<<gN, 256, 0, stream>>>(cnt);
    count_k<<<gE, 256, 0, stream>>>(ei, cnt);
    dinv_k<<<gN, 256, 0, stream>>>(cnt, dinv);
    scan_k<<<1, 256, 0, stream>>>(cnt, row_ptr, wptr);
    scatter_k<<<gET, 256, 0, stream>>>(ei, dinv, wptr, cols, norms);

    // ---- layer 1: h = x @ W1.T + b1 ; h = relu(appnp(h)) ----
    gemm128_k<<<512, 256, 0, stream>>>(x, W1, b1, H0, NN);
    {
        const float* cur = H0;
        for (int k = 0; k < 10; ++k) {
            float* dst = (k & 1) ? HB : HA;
            appnp_step_k<<<gStep, 256, 0, stream>>>(cur, H0, dst, row_ptr, cols,
                                                    norms, (k == 9) ? 1 : 0);
            cur = dst;
        }
    }
    // cur == HB (relu'd)

    // ---- layer 2: h = h @ W2.T + b2 ; h = relu(appnp(h)) ----
    gemm128_k<<<512, 256, 0, stream>>>(HB, W2, b2, H0, NN);
    {
        const float* cur = H0;
        for (int k = 0; k < 10; ++k) {
            float* dst = (k & 1) ? HB : HA;
            appnp_step_k<<<gStep, 256, 0, stream>>>(cur, H0, dst, row_ptr, cols,
                                                    norms, (k == 9) ? 1 : 0);
            cur = dst;
        }
    }
    // result in HB (relu'd)

    // ---- pair head ----
    pair_k<<<gPair, 256, 0, stream>>>(HB, idx, W3, b3, out);
}

// Round 2
// 998.999 us; speedup vs baseline: 1.7543x; 1.7543x over previous
//
#include <hip/hip_runtime.h>
#include <math.h>

#define NN 50000      // nodes
#define NE 800000     // edges
#define NP 200000     // link pairs
#define NF 128        // feature dim
#define NEDGE_TOT (NE + NN)   // edges + self loops
#define NBLK 196              // ceil(NN/256)

// ---- bf16 helpers (manual, RNE) ----
__device__ __forceinline__ float bf_lo(unsigned u) { return __uint_as_float(u << 16); }
__device__ __forceinline__ float bf_hi(unsigned u) { return __uint_as_float(u & 0xffff0000u); }
__device__ __forceinline__ unsigned short f2bf(float f) {
    unsigned u = __float_as_uint(f);
    return (unsigned short)((u + 0x7fffu + ((u >> 16) & 1u)) >> 16);
}
__device__ __forceinline__ unsigned pack2bf(float a, float b) {
    return (unsigned)f2bf(a) | ((unsigned)f2bf(b) << 16);
}

// ---------------------------------------------------------------------------
// CSR build
// ---------------------------------------------------------------------------
__global__ __launch_bounds__(256) void init_cnt_k(int* __restrict__ cnt) {
    int i = blockIdx.x * 256 + threadIdx.x;
    if (i < NN) cnt[i] = 1;  // self-loop
}

__global__ __launch_bounds__(256) void count_k(const int* __restrict__ ei,
                                               int* __restrict__ cnt) {
    int e = blockIdx.x * 256 + threadIdx.x;
    if (e < NE) atomicAdd(&cnt[ei[NE + e]], 1);
}

__global__ __launch_bounds__(256) void dinv_k(const int* __restrict__ cnt,
                                              float* __restrict__ dinv) {
    int i = blockIdx.x * 256 + threadIdx.x;
    if (i < NN) dinv[i] = rsqrtf((float)cnt[i]);
}

// hierarchical scan: reduce -> scan partials -> downsweep
__global__ __launch_bounds__(256) void scan_reduce_k(const int* __restrict__ cnt,
                                                     int* __restrict__ bsum) {
    __shared__ int s[256];
    int t = threadIdx.x;
    int idx = blockIdx.x * 256 + t;
    s[t] = (idx < NN) ? cnt[idx] : 0;
    __syncthreads();
    for (int off = 128; off > 0; off >>= 1) {
        if (t < off) s[t] += s[t + off];
        __syncthreads();
    }
    if (t == 0) bsum[blockIdx.x] = s[0];
}

__global__ __launch_bounds__(256) void scan_bsums_k(const int* __restrict__ bsum,
                                                    int* __restrict__ boff) {
    __shared__ int s[256];
    int t = threadIdx.x;
    int v = (t < NBLK) ? bsum[t] : 0;
    s[t] = v;
    __syncthreads();
    for (int off = 1; off < 256; off <<= 1) {
        int add = (t >= off) ? s[t - off] : 0;
        __syncthreads();
        s[t] += add;
        __syncthreads();
    }
    if (t < NBLK) boff[t] = s[t] - v;  // exclusive
}

__global__ __launch_bounds__(256) void scan_down_k(const int* __restrict__ cnt,
                                                   const int* __restrict__ boff,
                                                   int* __restrict__ row_ptr,
                                                   int* __restrict__ wptr) {
    __shared__ int s[256];
    int t = threadIdx.x;
    int idx = blockIdx.x * 256 + t;
    int v = (idx < NN) ? cnt[idx] : 0;
    s[t] = v;
    __syncthreads();
    for (int off = 1; off < 256; off <<= 1) {
        int add = (t >= off) ? s[t - off] : 0;
        __syncthreads();
        s[t] += add;
        __syncthreads();
    }
    int excl = s[t] - v + boff[blockIdx.x];
    if (idx < NN) {
        row_ptr[idx] = excl;
        wptr[idx] = excl;
        if (idx == NN - 1) row_ptr[NN] = excl + v;
    }
}

__global__ __launch_bounds__(256) void scatter_k(const int* __restrict__ ei,
                                                 const float* __restrict__ dinv,
                                                 int* __restrict__ wptr,
                                                 int* __restrict__ cols,
                                                 float* __restrict__ norms) {
    int e = blockIdx.x * 256 + threadIdx.x;
    if (e >= NEDGE_TOT) return;
    int s, d;
    if (e < NE) { s = ei[e]; d = ei[NE + e]; }
    else        { s = d = e - NE; }
    int pos = atomicAdd(&wptr[d], 1);
    cols[pos]  = s;
    norms[pos] = dinv[s] * dinv[d];
}

// ---------------------------------------------------------------------------
// GEMM: Y[n,f] = sum_d X[n,d]*W[f,d] + bias[f]; Y stored bf16.
// X is fp32 (layer 1) or bf16 (layer 2), selected by template.
// W staged transposed+swizzled in LDS (64 KiB): sW[d*128 + (f ^ (d&31))].
// ---------------------------------------------------------------------------
template <bool BF16IN>
__global__ __launch_bounds__(256) void gemm128_k(const void* __restrict__ Xv,
                                                 const float* __restrict__ W,
                                                 const float* __restrict__ bias,
                                                 unsigned short* __restrict__ Y,
                                                 int nrows) {
    __shared__ float sW[128 * 128];
    for (int i = threadIdx.x; i < 128 * 128; i += 256) {
        int f = i >> 7, d = i & 127;
        sW[d * 128 + (f ^ (d & 31))] = W[i];
    }
    __syncthreads();
    int f = threadIdx.x & 127;
    int half = threadIdx.x >> 7;
    float bf = bias[f];
    for (int base = blockIdx.x * 4; base < nrows; base += gridDim.x * 4) {
        int r0 = base + half * 2;
        float acc0 = 0.f, acc1 = 0.f;
#pragma unroll
        for (int d = 0; d < 128; d += 4) {
            float x0a, x1a, x2a, x3a, x0b, x1b, x2b, x3b;
            if (BF16IN) {
                const unsigned short* X = (const unsigned short*)Xv;
                uint2 qa = *(const uint2*)(X + (size_t)r0 * NF + d);
                uint2 qb = *(const uint2*)(X + (size_t)(r0 + 1) * NF + d);
                x0a = bf_lo(qa.x); x1a = bf_hi(qa.x); x2a = bf_lo(qa.y); x3a = bf_hi(qa.y);
                x0b = bf_lo(qb.x); x1b = bf_hi(qb.x); x2b = bf_lo(qb.y); x3b = bf_hi(qb.y);
            } else {
                const float* X = (const float*)Xv;
                float4 xa = *(const float4*)(X + (size_t)r0 * NF + d);
                float4 xb = *(const float4*)(X + (size_t)(r0 + 1) * NF + d);
                x0a = xa.x; x1a = xa.y; x2a = xa.z; x3a = xa.w;
                x0b = xb.x; x1b = xb.y; x2b = xb.z; x3b = xb.w;
            }
            float w0 = sW[(d + 0) * 128 + (f ^ ((d + 0) & 31))];
            float w1 = sW[(d + 1) * 128 + (f ^ ((d + 1) & 31))];
            float w2 = sW[(d + 2) * 128 + (f ^ ((d + 2) & 31))];
            float w3 = sW[(d + 3) * 128 + (f ^ ((d + 3) & 31))];
            acc0 += w0 * x0a + w1 * x1a + w2 * x2a + w3 * x3a;
            acc1 += w0 * x0b + w1 * x1b + w2 * x2b + w3 * x3b;
        }
        Y[(size_t)r0 * NF + f] = f2bf(acc0 + bf);
        Y[(size_t)(r0 + 1) * NF + f] = f2bf(acc1 + bf);
    }
}

// ---------------------------------------------------------------------------
// APPNP step, bf16 h: out[v] = 0.9 * sum_e norm_e * h[col_e] + 0.1 * x0[v]
// One wave per dst node. Two edges per gather instruction: lanes 0-31 take the
// even edge, 32-63 the odd edge; each lane loads 4 features (8 B). Cross-half
// merge via shfl_xor(32) at the end. fp32 accumulation.
// ---------------------------------------------------------------------------
__global__ __launch_bounds__(256) void appnp_bf16_k(const unsigned short* __restrict__ h,
                                                    const unsigned short* __restrict__ x0,
                                                    unsigned short* __restrict__ out,
                                                    const int* __restrict__ row_ptr,
                                                    const int* __restrict__ cols,
                                                    const float* __restrict__ norms,
                                                    int relu) {
    int wid = (blockIdx.x * 256 + threadIdx.x) >> 6;
    int lane = threadIdx.x & 63;
    if (wid >= NN) return;
    int half = lane >> 5, li = lane & 31;
    int beg = row_ptr[wid], end = row_ptr[wid + 1];
    float a0 = 0.f, a1 = 0.f, a2 = 0.f, a3 = 0.f;
    for (int e = beg; e < end; e += 64) {
        int m = end - e;
        if (m > 64) m = 64;
        int c = 0;
        float w = 0.f;
        if (lane < m) { c = cols[e + lane]; w = norms[e + lane]; }
        for (int j = 0; j < m; j += 8) {
#pragma unroll
            for (int p = 0; p < 4; ++p) {
                int src = j + 2 * p + half;           // lanes >= m carry w=0,c=0
                int cj = __shfl(c, src, 64);
                float wj = __shfl(w, src, 64);
                uint2 q = *((const uint2*)(h + (size_t)cj * NF) + li);
                a0 += wj * bf_lo(q.x);
                a1 += wj * bf_hi(q.x);
                a2 += wj * bf_lo(q.y);
                a3 += wj * bf_hi(q.y);
            }
        }
    }
    a0 += __shfl_xor(a0, 32, 64);
    a1 += __shfl_xor(a1, 32, 64);
    a2 += __shfl_xor(a2, 32, 64);
    a3 += __shfl_xor(a3, 32, 64);
    if (half == 0) {
        uint2 xq = *((const uint2*)(x0 + (size_t)wid * NF) + li);
        float r0 = 0.9f * a0 + 0.1f * bf_lo(xq.x);
        float r1 = 0.9f * a1 + 0.1f * bf_hi(xq.x);
        float r2 = 0.9f * a2 + 0.1f * bf_lo(xq.y);
        float r3 = 0.9f * a3 + 0.1f * bf_hi(xq.y);
        if (relu) {
            r0 = fmaxf(r0, 0.f); r1 = fmaxf(r1, 0.f);
            r2 = fmaxf(r2, 0.f); r3 = fmaxf(r3, 0.f);
        }
        uint2 oq;
        oq.x = pack2bf(r0, r1);
        oq.y = pack2bf(r2, r3);
        *((uint2*)(out + (size_t)wid * NF) + li) = oq;
    }
}

// ---------------------------------------------------------------------------
// Pair head: one wave per pair; lanes 0-31 hold h[u], 32-63 hold h[v] (4 feats
// each, 8 B loads). Butterfly-reduce both logits; lane 0 writes log_softmax.
// ---------------------------------------------------------------------------
__global__ __launch_bounds__(256) void pair_k(const unsigned short* __restrict__ h,
                                              const int* __restrict__ index,
                                              const float* __restrict__ W3,
                                              const float* __restrict__ b3,
                                              float* __restrict__ outp) {
    int gw = (blockIdx.x * 256 + threadIdx.x) >> 6;
    int lane = threadIdx.x & 63;
    if (gw >= NP) return;
    int half = lane >> 5, li = lane & 31;
    int u = index[gw * 2], v = index[gw * 2 + 1];
    int node = half ? v : u;
    uint2 q = *((const uint2*)(h + (size_t)node * NF) + li);
    float f0 = bf_lo(q.x), f1 = bf_hi(q.x), f2 = bf_lo(q.y), f3 = bf_hi(q.y);
    int fb = half * 128 + li * 4;                    // index into concat space
    float4 wa = *(const float4*)(W3 + fb);
    float4 wb = *(const float4*)(W3 + 256 + fb);
    float p0 = f0 * wa.x + f1 * wa.y + f2 * wa.z + f3 * wa.w;
    float p1 = f0 * wb.x + f1 * wb.y + f2 * wb.z + f3 * wb.w;
#pragma unroll
    for (int off = 32; off > 0; off >>= 1) {
        p0 += __shfl_xor(p0, off, 64);
        p1 += __shfl_xor(p1, off, 64);
    }
    if (lane == 0) {
        float s0 = p0 + b3[0], s1 = p1 + b3[1];
        float m = fmaxf(s0, s1);
        float lse = m + logf(expf(s0 - m) + expf(s1 - m));
        *(float2*)(outp + (size_t)gw * 2) = make_float2(s0 - lse, s1 - lse);
    }
}

// ---------------------------------------------------------------------------
// Launch
// ---------------------------------------------------------------------------
extern "C" void kernel_launch(void* const* d_in, const int* in_sizes, int n_in,
                              void* d_out, int out_size, void* d_ws, size_t ws_size,
                              hipStream_t stream) {
    const float* x  = (const float*)d_in[0];
    const int* ei   = (const int*)d_in[1];
    const int* idx  = (const int*)d_in[2];
    const float* W1 = (const float*)d_in[3];
    const float* b1 = (const float*)d_in[4];
    const float* W2 = (const float*)d_in[5];
    const float* b2 = (const float*)d_in[6];
    const float* W3 = (const float*)d_in[7];
    const float* b3 = (const float*)d_in[8];
    float* out = (float*)d_out;

    char* ws = (char*)d_ws;
    size_t off = 0;
    auto alloc = [&](size_t bytes) -> void* {
        void* p = ws + off;
        off = (off + bytes + 255) & ~(size_t)255;
        return p;
    };
    int*   cnt     = (int*)  alloc(NN * sizeof(int));
    float* dinv    = (float*)alloc(NN * sizeof(float));
    int*   row_ptr = (int*)  alloc((NN + 1) * sizeof(int));
    int*   wptr    = (int*)  alloc(NN * sizeof(int));
    int*   bsum    = (int*)  alloc(NBLK * sizeof(int));
    int*   boff    = (int*)  alloc(NBLK * sizeof(int));
    int*   cols    = (int*)  alloc(NEDGE_TOT * sizeof(int));
    float* norms   = (float*)alloc(NEDGE_TOT * sizeof(float));
    unsigned short* H0 = (unsigned short*)alloc((size_t)NN * NF * 2);
    unsigned short* HA = (unsigned short*)alloc((size_t)NN * NF * 2);
    unsigned short* HB = (unsigned short*)alloc((size_t)NN * NF * 2);

    const int gN    = (NN + 255) / 256;          // 196
    const int gE    = (NE + 255) / 256;
    const int gET   = (NEDGE_TOT + 255) / 256;
    const int gStep = (NN * 64 + 255) / 256;     // wave per node
    const int gPair = (NP * 64 + 255) / 256;     // wave per pair

    // ---- gcn_norm + CSR ----
    init_cnt_k<<<gN, 256, 0, stream>>>(cnt);
    count_k<<<gE, 256, 0, stream>>>(ei, cnt);
    dinv_k<<<gN, 256, 0, stream>>>(cnt, dinv);
    scan_reduce_k<<<NBLK, 256, 0, stream>>>(cnt, bsum);
    scan_bsums_k<<<1, 256, 0, stream>>>(bsum, boff);
    scan_down_k<<<NBLK, 256, 0, stream>>>(cnt, boff, row_ptr, wptr);
    scatter_k<<<gET, 256, 0, stream>>>(ei, dinv, wptr, cols, norms);

    // ---- layer 1 ----
    gemm128_k<false><<<512, 256, 0, stream>>>(x, W1, b1, H0, NN);
    {
        const unsigned short* cur = H0;
        for (int k = 0; k < 10; ++k) {
            unsigned short* dst = (k & 1) ? HB : HA;
            appnp_bf16_k<<<gStep, 256, 0, stream>>>(cur, H0, dst, row_ptr, cols,
                                                    norms, (k == 9) ? 1 : 0);
            cur = dst;
        }
    }
    // ---- layer 2 ----
    gemm128_k<true><<<512, 256, 0, stream>>>(HB, W2, b2, H0, NN);
    {
        const unsigned short* cur = H0;
        for (int k = 0; k < 10; ++k) {
            unsigned short* dst = (k & 1) ? HB : HA;
            appnp_bf16_k<<<gStep, 256, 0, stream>>>(cur, H0, dst, row_ptr, cols,
                                                    norms, (k == 9) ? 1 : 0);
            cur = dst;
        }
    }
    // ---- pair head ----
    pair_k<<<gPair, 256, 0, stream>>>(HB, idx, W3, b3, out);
}